// Round 3
// baseline (470.009 us; speedup 1.0000x reference)
//
#include <hip/hip_runtime.h>

#define N_NODES   50000
#define N_EDGES   800000
#define IN_CH     128
#define HID       64
#define N_GRAPHS  64
#define N_CLASSES 2

// NOTE: harness delivers ALL integer inputs as int32 (int64 in the JAX ref is
// converted). Reading them as long long caused a GPU page fault in round 2.

// ---------------------------------------------------------------------------
// K0: in-degree count (real edges only; self-loop handled analytically)
// ---------------------------------------------------------------------------
__global__ void deg_kernel(const int* __restrict__ ei, int* __restrict__ degCount) {
    int e = blockIdx.x * blockDim.x + threadIdx.x;
    if (e < N_EDGES) {
        int dst = ei[N_EDGES + e];
        atomicAdd(&degCount[dst], 1);
    }
}

// ---------------------------------------------------------------------------
// K1: single-block exclusive scan over degCount -> rowPtr, plus fillPtr
//     (aliased onto degCount storage) and dinv = (deg+1)^-0.5
// ---------------------------------------------------------------------------
__global__ __launch_bounds__(1024) void scan_kernel(int* __restrict__ degCount, // in: counts, out: fillPtr
                                                    int* __restrict__ rowPtr,
                                                    float* __restrict__ dinv) {
    __shared__ int sums[1024];
    const int n = N_NODES;
    const int chunk = (n + 1023) / 1024;          // 49
    int t = threadIdx.x;
    int c0 = t * chunk;
    int c1 = min(c0 + chunk, n);
    if (c0 >= n) c1 = c0;

    int s = 0;
    for (int i = c0; i < c1; ++i) s += degCount[i];
    sums[t] = s;
    __syncthreads();
    // Hillis-Steele inclusive scan over 1024 partials
    for (int off = 1; off < 1024; off <<= 1) {
        int v = (t >= off) ? sums[t - off] : 0;
        __syncthreads();
        sums[t] += v;
        __syncthreads();
    }
    int prefix = (t == 0) ? 0 : sums[t - 1];
    for (int i = c0; i < c1; ++i) {
        int d = degCount[i];                      // read count...
        rowPtr[i]   = prefix;
        degCount[i] = prefix;                     // ...then overwrite as fillPtr
        dinv[i]     = 1.0f / sqrtf((float)(d + 1));
        prefix += d;
    }
    if (c0 < n && c1 == n) rowPtr[n] = prefix;    // total == N_EDGES
}

// ---------------------------------------------------------------------------
// K2: CSR fill (colIdx[pos] = src for each dst)
// ---------------------------------------------------------------------------
__global__ void fill_kernel(const int* __restrict__ ei,
                            int* __restrict__ fillPtr, int* __restrict__ colIdx) {
    int e = blockIdx.x * blockDim.x + threadIdx.x;
    if (e < N_EDGES) {
        int src = ei[e];
        int dst = ei[N_EDGES + e];
        int pos = atomicAdd(&fillPtr[dst], 1);
        colIdx[pos] = src;
    }
}

// ---------------------------------------------------------------------------
// K3/K5: g = (A @ W) * dinv[row]     A:[N,K]  W:[K,64]  g:[N,64]
// Block = 256 threads = 16 col-chunks (c4: 4 cols each) x 16 row-groups of
// R=8 rows -> 128 rows/block. W staged in LDS; each LDS W-read is amortized
// over 8 rows (32 fma per ds_read_b128) -> VALU-bound, not LDS-bound.
// Global A loads: 16 lanes share an address -> coalescer dedups to 16B/row.
// ---------------------------------------------------------------------------
#define FMA4(xs, w, a) { (a).x = fmaf((xs), (w).x, (a).x); \
                         (a).y = fmaf((xs), (w).y, (a).y); \
                         (a).z = fmaf((xs), (w).z, (a).z); \
                         (a).w = fmaf((xs), (w).w, (a).w); }

template <int K>
__global__ __launch_bounds__(256) void gemm_kernel(const float* __restrict__ A,
                                                   const float* __restrict__ W,
                                                   const float* __restrict__ dinv,
                                                   float* __restrict__ out) {
    __shared__ float4 Ws[K * 16];                 // [K][64] floats as float4[16]
    for (int i = threadIdx.x; i < K * 16; i += 256)
        Ws[i] = ((const float4*)W)[i];
    __syncthreads();

    const int c4   = threadIdx.x & 15;
    const int rg   = threadIdx.x >> 4;            // 0..15
    const int row0 = blockIdx.x * 128 + rg * 8;

    const float4* ap[8];
#pragma unroll
    for (int r = 0; r < 8; ++r) {
        int rowc = min(row0 + r, N_NODES - 1);    // clamp: OOB rows load row N-1
        ap[r] = (const float4*)(A + (size_t)rowc * K);
    }

    float4 acc[8] = {};
    for (int kk = 0; kk < K / 4; ++kk) {
        float4 xv[8];
#pragma unroll
        for (int r = 0; r < 8; ++r) xv[r] = ap[r][kk];
        float4 w;
        w = Ws[(4 * kk + 0) * 16 + c4];
#pragma unroll
        for (int r = 0; r < 8; ++r) FMA4(xv[r].x, w, acc[r]);
        w = Ws[(4 * kk + 1) * 16 + c4];
#pragma unroll
        for (int r = 0; r < 8; ++r) FMA4(xv[r].y, w, acc[r]);
        w = Ws[(4 * kk + 2) * 16 + c4];
#pragma unroll
        for (int r = 0; r < 8; ++r) FMA4(xv[r].z, w, acc[r]);
        w = Ws[(4 * kk + 3) * 16 + c4];
#pragma unroll
        for (int r = 0; r < 8; ++r) FMA4(xv[r].w, w, acc[r]);
    }

#pragma unroll
    for (int r = 0; r < 8; ++r) {
        int row = row0 + r;
        if (row < N_NODES) {
            float dv = dinv[row];
            float4 o = acc[r];
            o.x *= dv; o.y *= dv; o.z *= dv; o.w *= dv;
            ((float4*)(out + (size_t)row * HID))[c4] = o;
        }
    }
}

// ---------------------------------------------------------------------------
// K4/K6: aggregation. One wave per node, lane = channel.
// out[v] = relu(dinv[v] * (g[v] + sum_{u->v} g[u]) + bias)
// ---------------------------------------------------------------------------
__global__ __launch_bounds__(256) void agg_kernel(const float* __restrict__ g,
                                                  const float* __restrict__ dinv,
                                                  const int* __restrict__ rowPtr,
                                                  const int* __restrict__ colIdx,
                                                  const float* __restrict__ bias,
                                                  float* __restrict__ out) {
    int lane = threadIdx.x & 63;
    int v = blockIdx.x * 4 + (threadIdx.x >> 6);
    if (v >= N_NODES) return;

    float acc = g[(size_t)v * HID + lane];
    int e  = rowPtr[v];
    int e1 = rowPtr[v + 1];
    // 4-wide batches of independent loads for latency hiding
    for (; e + 3 < e1; e += 4) {
        int u0 = colIdx[e], u1 = colIdx[e + 1], u2 = colIdx[e + 2], u3 = colIdx[e + 3];
        float a0 = g[(size_t)u0 * HID + lane];
        float a1 = g[(size_t)u1 * HID + lane];
        float a2 = g[(size_t)u2 * HID + lane];
        float a3 = g[(size_t)u3 * HID + lane];
        acc += (a0 + a1) + (a2 + a3);
    }
    for (; e < e1; ++e) acc += g[(size_t)colIdx[e] * HID + lane];

    float r = dinv[v] * acc + bias[lane];
    out[(size_t)v * HID + lane] = fmaxf(r, 0.f);
}

// ---------------------------------------------------------------------------
// K7: per-graph mean pool (batch is sorted) + linear head.
// One block per graph; boundaries via binary search.
// d_out layout: [ out (64x2) | pooled (64x64) ]
// ---------------------------------------------------------------------------
__global__ __launch_bounds__(256) void pool_kernel(const float* __restrict__ h,
                                                   const int* __restrict__ batch,
                                                   const float* __restrict__ Wl,
                                                   const float* __restrict__ bl,
                                                   float* __restrict__ dout) {
    __shared__ int bounds[2];
    __shared__ float red[4][64];
    int g = blockIdx.x;
    if (threadIdx.x < 2) {
        int target = g + (int)threadIdx.x;
        int lo = 0, hi = N_NODES;
        while (lo < hi) {
            int mid = (lo + hi) >> 1;
            if (batch[mid] < target) lo = mid + 1; else hi = mid;
        }
        bounds[threadIdx.x] = lo;
    }
    __syncthreads();
    int start = bounds[0], end = bounds[1];
    int lane = threadIdx.x & 63, w = threadIdx.x >> 6;

    float acc = 0.f;
    for (int r = start + w; r < end; r += 4)
        acc += h[(size_t)r * HID + lane];
    red[w][lane] = acc;
    __syncthreads();
    if (w == 0) {
        float s = red[0][lane] + red[1][lane] + red[2][lane] + red[3][lane];
        float cnt = (float)(end - start);
        float p = s / fmaxf(cnt, 1.0f);
        dout[N_GRAPHS * N_CLASSES + g * HID + lane] = p;
        red[0][lane] = p;
    }
    __syncthreads();
    if (threadIdx.x < N_CLASSES) {
        float o = bl[threadIdx.x];
        for (int k = 0; k < HID; ++k)
            o = fmaf(red[0][k], Wl[k * N_CLASSES + threadIdx.x], o);
        dout[g * N_CLASSES + threadIdx.x] = o;
    }
}

// ---------------------------------------------------------------------------
extern "C" void kernel_launch(void* const* d_in, const int* in_sizes, int n_in,
                              void* d_out, int out_size, void* d_ws, size_t ws_size,
                              hipStream_t stream) {
    const float* x     = (const float*)d_in[0];
    const int*   ei    = (const int*)d_in[1];    // int32 on device (harness converts int64)
    const int*   batch = (const int*)d_in[2];    // int32 on device
    const float* W1    = (const float*)d_in[3];
    const float* b1    = (const float*)d_in[4];
    const float* W2    = (const float*)d_in[5];
    const float* b2    = (const float*)d_in[6];
    const float* Wl    = (const float*)d_in[7];
    const float* bl    = (const float*)d_in[8];
    float* out = (float*)d_out;

    char* ws = (char*)d_ws;
    size_t off = 0;
    auto alloc = [&](size_t bytes) -> void* {
        void* p = ws + off;
        off += (bytes + 255) & ~(size_t)255;
        return p;
    };
    int*   degFill = (int*)  alloc((size_t)N_NODES * 4);          // counts -> fillPtr
    int*   rowPtr  = (int*)  alloc((size_t)(N_NODES + 1) * 4);
    float* dinv    = (float*)alloc((size_t)N_NODES * 4);
    int*   colIdx  = (int*)  alloc((size_t)N_EDGES * 4);
    float* bufA    = (float*)alloc((size_t)N_NODES * HID * 4);    // g1 -> g2
    float* bufB    = (float*)alloc((size_t)N_NODES * HID * 4);    // h1 -> h2

    hipMemsetAsync(degFill, 0, (size_t)N_NODES * 4, stream);

    deg_kernel <<<(N_EDGES + 255) / 256, 256, 0, stream>>>(ei, degFill);
    scan_kernel<<<1, 1024, 0, stream>>>(degFill, rowPtr, dinv);
    fill_kernel<<<(N_EDGES + 255) / 256, 256, 0, stream>>>(ei, degFill, colIdx);

    // layer 1: g1 = (x@W1)*dinv ; h1 = relu(dinv*(g1[v]+sum g1[u]) + b1)
    gemm_kernel<IN_CH><<<(N_NODES + 127) / 128, 256, 0, stream>>>(x, W1, dinv, bufA);
    agg_kernel        <<<N_NODES / 4, 256, 0, stream>>>(bufA, dinv, rowPtr, colIdx, b1, bufB);

    // layer 2
    gemm_kernel<HID>  <<<(N_NODES + 127) / 128, 256, 0, stream>>>(bufB, W2, dinv, bufA);
    agg_kernel        <<<N_NODES / 4, 256, 0, stream>>>(bufA, dinv, rowPtr, colIdx, b2, bufB);

    // pool + head
    pool_kernel<<<N_GRAPHS, 256, 0, stream>>>(bufB, batch, Wl, bl, out);
}

// Round 4
// 348.275 us; speedup vs baseline: 1.3495x; 1.3495x over previous
//
#include <hip/hip_runtime.h>

#define N_NODES   50000
#define N_EDGES   800000
#define IN_CH     128
#define HID       64
#define N_GRAPHS  64
#define N_CLASSES 2
#define NBLK_SCAN ((N_NODES + 255) / 256)   // 196

// NOTE: harness delivers ALL integer inputs as int32 (int64 in the JAX ref is
// converted). Reading them as long long caused a GPU page fault in round 2.
// Round 3: single-block scan_kernel was 133 us (28% of total, 0.14% occupancy)
// -> replaced with 3-phase multi-block scan.

// ---------------------------------------------------------------------------
// K0: in-degree count (real edges only; self-loop handled analytically)
// ---------------------------------------------------------------------------
__global__ void deg_kernel(const int* __restrict__ ei, int* __restrict__ degCount) {
    int e = blockIdx.x * blockDim.x + threadIdx.x;
    if (e < N_EDGES) {
        int dst = ei[N_EDGES + e];
        atomicAdd(&degCount[dst], 1);
    }
}

// ---------------------------------------------------------------------------
// K1a: per-256-chunk sums
// ---------------------------------------------------------------------------
__global__ __launch_bounds__(256) void scan1_kernel(const int* __restrict__ degCount,
                                                    int* __restrict__ blockSums) {
    __shared__ int red[256];
    int i = blockIdx.x * 256 + threadIdx.x;
    red[threadIdx.x] = (i < N_NODES) ? degCount[i] : 0;
    __syncthreads();
    for (int off = 128; off > 0; off >>= 1) {
        if (threadIdx.x < off) red[threadIdx.x] += red[threadIdx.x + off];
        __syncthreads();
    }
    if (threadIdx.x == 0) blockSums[blockIdx.x] = red[0];
}

// ---------------------------------------------------------------------------
// K1b: single-block exclusive scan over the 196 block sums
// ---------------------------------------------------------------------------
__global__ __launch_bounds__(256) void scan2_kernel(int* __restrict__ blockSums) {
    __shared__ int s[256];
    int t = threadIdx.x;
    int v = (t < NBLK_SCAN) ? blockSums[t] : 0;
    s[t] = v;
    __syncthreads();
    for (int off = 1; off < 256; off <<= 1) {
        int a = (t >= off) ? s[t - off] : 0;
        __syncthreads();
        s[t] += a;
        __syncthreads();
    }
    if (t < NBLK_SCAN) blockSums[t] = s[t] - v;   // exclusive prefix
}

// ---------------------------------------------------------------------------
// K1c: per-chunk exclusive scan + block offset -> rowPtr, fillPtr (aliased
//      onto degCount), dinv = (deg+1)^-0.5
// ---------------------------------------------------------------------------
__global__ __launch_bounds__(256) void scan3_kernel(int* __restrict__ degFill,  // in: counts, out: fillPtr
                                                    const int* __restrict__ blockSums,
                                                    int* __restrict__ rowPtr,
                                                    float* __restrict__ dinv) {
    __shared__ int s[256];
    int t = threadIdx.x;
    int i = blockIdx.x * 256 + t;
    int d = (i < N_NODES) ? degFill[i] : 0;
    s[t] = d;
    __syncthreads();
    for (int off = 1; off < 256; off <<= 1) {
        int a = (t >= off) ? s[t - off] : 0;
        __syncthreads();
        s[t] += a;
        __syncthreads();
    }
    int excl = s[t] - d + blockSums[blockIdx.x];
    if (i < N_NODES) {
        rowPtr[i]  = excl;
        degFill[i] = excl;
        dinv[i]    = 1.0f / sqrtf((float)(d + 1));
    }
    if (i == 0) rowPtr[N_NODES] = N_EDGES;        // all edges retained
}

// ---------------------------------------------------------------------------
// K2: CSR fill (colIdx[pos] = src for each dst)
// ---------------------------------------------------------------------------
__global__ void fill_kernel(const int* __restrict__ ei,
                            int* __restrict__ fillPtr, int* __restrict__ colIdx) {
    int e = blockIdx.x * blockDim.x + threadIdx.x;
    if (e < N_EDGES) {
        int src = ei[e];
        int dst = ei[N_EDGES + e];
        int pos = atomicAdd(&fillPtr[dst], 1);
        colIdx[pos] = src;
    }
}

// ---------------------------------------------------------------------------
// K3/K5: g = (A @ W) * dinv[row]     A:[N,K]  W:[K,64]  g:[N,64]
// Block = 256 threads = 16 col-chunks (c4: 4 cols each) x 16 row-groups of
// R=8 rows -> 128 rows/block. W staged in LDS; each LDS W-read is amortized
// over 8 rows (32 fma per ds_read_b128) -> VALU-bound, not LDS-bound.
// ---------------------------------------------------------------------------
#define FMA4(xs, w, a) { (a).x = fmaf((xs), (w).x, (a).x); \
                         (a).y = fmaf((xs), (w).y, (a).y); \
                         (a).z = fmaf((xs), (w).z, (a).z); \
                         (a).w = fmaf((xs), (w).w, (a).w); }

template <int K>
__global__ __launch_bounds__(256) void gemm_kernel(const float* __restrict__ A,
                                                   const float* __restrict__ W,
                                                   const float* __restrict__ dinv,
                                                   float* __restrict__ out) {
    __shared__ float4 Ws[K * 16];                 // [K][64] floats as float4[16]
    for (int i = threadIdx.x; i < K * 16; i += 256)
        Ws[i] = ((const float4*)W)[i];
    __syncthreads();

    const int c4   = threadIdx.x & 15;
    const int rg   = threadIdx.x >> 4;            // 0..15
    const int row0 = blockIdx.x * 128 + rg * 8;

    const float4* ap[8];
#pragma unroll
    for (int r = 0; r < 8; ++r) {
        int rowc = min(row0 + r, N_NODES - 1);    // clamp: OOB rows load row N-1
        ap[r] = (const float4*)(A + (size_t)rowc * K);
    }

    float4 acc[8] = {};
    for (int kk = 0; kk < K / 4; ++kk) {
        float4 xv[8];
#pragma unroll
        for (int r = 0; r < 8; ++r) xv[r] = ap[r][kk];
        float4 w;
        w = Ws[(4 * kk + 0) * 16 + c4];
#pragma unroll
        for (int r = 0; r < 8; ++r) FMA4(xv[r].x, w, acc[r]);
        w = Ws[(4 * kk + 1) * 16 + c4];
#pragma unroll
        for (int r = 0; r < 8; ++r) FMA4(xv[r].y, w, acc[r]);
        w = Ws[(4 * kk + 2) * 16 + c4];
#pragma unroll
        for (int r = 0; r < 8; ++r) FMA4(xv[r].z, w, acc[r]);
        w = Ws[(4 * kk + 3) * 16 + c4];
#pragma unroll
        for (int r = 0; r < 8; ++r) FMA4(xv[r].w, w, acc[r]);
    }

#pragma unroll
    for (int r = 0; r < 8; ++r) {
        int row = row0 + r;
        if (row < N_NODES) {
            float dv = dinv[row];
            float4 o = acc[r];
            o.x *= dv; o.y *= dv; o.z *= dv; o.w *= dv;
            ((float4*)(out + (size_t)row * HID))[c4] = o;
        }
    }
}

// ---------------------------------------------------------------------------
// K4/K6: aggregation. One wave per node, lane = channel.
// out[v] = relu(dinv[v] * (g[v] + sum_{u->v} g[u]) + bias)
// ---------------------------------------------------------------------------
__global__ __launch_bounds__(256) void agg_kernel(const float* __restrict__ g,
                                                  const float* __restrict__ dinv,
                                                  const int* __restrict__ rowPtr,
                                                  const int* __restrict__ colIdx,
                                                  const float* __restrict__ bias,
                                                  float* __restrict__ out) {
    int lane = threadIdx.x & 63;
    int v = blockIdx.x * 4 + (threadIdx.x >> 6);
    if (v >= N_NODES) return;

    float acc = g[(size_t)v * HID + lane];
    int e  = rowPtr[v];
    int e1 = rowPtr[v + 1];
    // 4-wide batches of independent loads for latency hiding
    for (; e + 3 < e1; e += 4) {
        int u0 = colIdx[e], u1 = colIdx[e + 1], u2 = colIdx[e + 2], u3 = colIdx[e + 3];
        float a0 = g[(size_t)u0 * HID + lane];
        float a1 = g[(size_t)u1 * HID + lane];
        float a2 = g[(size_t)u2 * HID + lane];
        float a3 = g[(size_t)u3 * HID + lane];
        acc += (a0 + a1) + (a2 + a3);
    }
    for (; e < e1; ++e) acc += g[(size_t)colIdx[e] * HID + lane];

    float r = dinv[v] * acc + bias[lane];
    out[(size_t)v * HID + lane] = fmaxf(r, 0.f);
}

// ---------------------------------------------------------------------------
// K7: per-graph mean pool (batch is sorted) + linear head.
// d_out layout: [ out (64x2) | pooled (64x64) ]
// ---------------------------------------------------------------------------
__global__ __launch_bounds__(256) void pool_kernel(const float* __restrict__ h,
                                                   const int* __restrict__ batch,
                                                   const float* __restrict__ Wl,
                                                   const float* __restrict__ bl,
                                                   float* __restrict__ dout) {
    __shared__ int bounds[2];
    __shared__ float red[4][64];
    int g = blockIdx.x;
    if (threadIdx.x < 2) {
        int target = g + (int)threadIdx.x;
        int lo = 0, hi = N_NODES;
        while (lo < hi) {
            int mid = (lo + hi) >> 1;
            if (batch[mid] < target) lo = mid + 1; else hi = mid;
        }
        bounds[threadIdx.x] = lo;
    }
    __syncthreads();
    int start = bounds[0], end = bounds[1];
    int lane = threadIdx.x & 63, w = threadIdx.x >> 6;

    float acc = 0.f;
    for (int r = start + w; r < end; r += 4)
        acc += h[(size_t)r * HID + lane];
    red[w][lane] = acc;
    __syncthreads();
    if (w == 0) {
        float s = red[0][lane] + red[1][lane] + red[2][lane] + red[3][lane];
        float cnt = (float)(end - start);
        float p = s / fmaxf(cnt, 1.0f);
        dout[N_GRAPHS * N_CLASSES + g * HID + lane] = p;
        red[0][lane] = p;
    }
    __syncthreads();
    if (threadIdx.x < N_CLASSES) {
        float o = bl[threadIdx.x];
        for (int k = 0; k < HID; ++k)
            o = fmaf(red[0][k], Wl[k * N_CLASSES + threadIdx.x], o);
        dout[g * N_CLASSES + threadIdx.x] = o;
    }
}

// ---------------------------------------------------------------------------
extern "C" void kernel_launch(void* const* d_in, const int* in_sizes, int n_in,
                              void* d_out, int out_size, void* d_ws, size_t ws_size,
                              hipStream_t stream) {
    const float* x     = (const float*)d_in[0];
    const int*   ei    = (const int*)d_in[1];    // int32 on device
    const int*   batch = (const int*)d_in[2];    // int32 on device
    const float* W1    = (const float*)d_in[3];
    const float* b1    = (const float*)d_in[4];
    const float* W2    = (const float*)d_in[5];
    const float* b2    = (const float*)d_in[6];
    const float* Wl    = (const float*)d_in[7];
    const float* bl    = (const float*)d_in[8];
    float* out = (float*)d_out;

    char* ws = (char*)d_ws;
    size_t off = 0;
    auto alloc = [&](size_t bytes) -> void* {
        void* p = ws + off;
        off += (bytes + 255) & ~(size_t)255;
        return p;
    };
    int*   degFill   = (int*)  alloc((size_t)N_NODES * 4);        // counts -> fillPtr
    int*   rowPtr    = (int*)  alloc((size_t)(N_NODES + 1) * 4);
    float* dinv      = (float*)alloc((size_t)N_NODES * 4);
    int*   blockSums = (int*)  alloc((size_t)NBLK_SCAN * 4);
    int*   colIdx    = (int*)  alloc((size_t)N_EDGES * 4);
    float* bufA      = (float*)alloc((size_t)N_NODES * HID * 4);  // g1 -> g2
    float* bufB      = (float*)alloc((size_t)N_NODES * HID * 4);  // h1 -> h2

    hipMemsetAsync(degFill, 0, (size_t)N_NODES * 4, stream);

    deg_kernel  <<<(N_EDGES + 255) / 256, 256, 0, stream>>>(ei, degFill);
    scan1_kernel<<<NBLK_SCAN, 256, 0, stream>>>(degFill, blockSums);
    scan2_kernel<<<1, 256, 0, stream>>>(blockSums);
    scan3_kernel<<<NBLK_SCAN, 256, 0, stream>>>(degFill, blockSums, rowPtr, dinv);
    fill_kernel <<<(N_EDGES + 255) / 256, 256, 0, stream>>>(ei, degFill, colIdx);

    // layer 1: g1 = (x@W1)*dinv ; h1 = relu(dinv*(g1[v]+sum g1[u]) + b1)
    gemm_kernel<IN_CH><<<(N_NODES + 127) / 128, 256, 0, stream>>>(x, W1, dinv, bufA);
    agg_kernel        <<<N_NODES / 4, 256, 0, stream>>>(bufA, dinv, rowPtr, colIdx, b1, bufB);

    // layer 2
    gemm_kernel<HID>  <<<(N_NODES + 127) / 128, 256, 0, stream>>>(bufB, W2, dinv, bufA);
    agg_kernel        <<<N_NODES / 4, 256, 0, stream>>>(bufA, dinv, rowPtr, colIdx, b2, bufB);

    // pool + head
    pool_kernel<<<N_GRAPHS, 256, 0, stream>>>(bufB, batch, Wl, bl, out);
}

// Round 5
// 332.980 us; speedup vs baseline: 1.4115x; 1.0459x over previous
//
#include <hip/hip_runtime.h>

#define N_NODES   50000
#define N_EDGES   800000
#define IN_CH     128
#define HID       64
#define N_GRAPHS  64
#define N_CLASSES 2
#define NBLK_SCAN ((N_NODES + 255) / 256)   // 196

// Round 3: single-block scan was 133 us -> 3-phase scan.
// Round 4: pool_kernel was 59 us at 2.3% occupancy (64 blocks, latency-bound)
// -> split into grid-wide atomic partial pool (P1) + tiny finalize (P2).

// ---------------------------------------------------------------------------
// K0: in-degree count (real edges only; self-loop handled analytically)
// ---------------------------------------------------------------------------
__global__ void deg_kernel(const int* __restrict__ ei, int* __restrict__ degCount) {
    int e = blockIdx.x * blockDim.x + threadIdx.x;
    if (e < N_EDGES) {
        int dst = ei[N_EDGES + e];
        atomicAdd(&degCount[dst], 1);
    }
}

// ---------------------------------------------------------------------------
// K1a: per-256-chunk sums
// ---------------------------------------------------------------------------
__global__ __launch_bounds__(256) void scan1_kernel(const int* __restrict__ degCount,
                                                    int* __restrict__ blockSums) {
    __shared__ int red[256];
    int i = blockIdx.x * 256 + threadIdx.x;
    red[threadIdx.x] = (i < N_NODES) ? degCount[i] : 0;
    __syncthreads();
    for (int off = 128; off > 0; off >>= 1) {
        if (threadIdx.x < off) red[threadIdx.x] += red[threadIdx.x + off];
        __syncthreads();
    }
    if (threadIdx.x == 0) blockSums[blockIdx.x] = red[0];
}

// ---------------------------------------------------------------------------
// K1b: single-block exclusive scan over the 196 block sums
// ---------------------------------------------------------------------------
__global__ __launch_bounds__(256) void scan2_kernel(int* __restrict__ blockSums) {
    __shared__ int s[256];
    int t = threadIdx.x;
    int v = (t < NBLK_SCAN) ? blockSums[t] : 0;
    s[t] = v;
    __syncthreads();
    for (int off = 1; off < 256; off <<= 1) {
        int a = (t >= off) ? s[t - off] : 0;
        __syncthreads();
        s[t] += a;
        __syncthreads();
    }
    if (t < NBLK_SCAN) blockSums[t] = s[t] - v;   // exclusive prefix
}

// ---------------------------------------------------------------------------
// K1c: per-chunk exclusive scan + block offset -> rowPtr, fillPtr (aliased
//      onto degCount), dinv = (deg+1)^-0.5
// ---------------------------------------------------------------------------
__global__ __launch_bounds__(256) void scan3_kernel(int* __restrict__ degFill,
                                                    const int* __restrict__ blockSums,
                                                    int* __restrict__ rowPtr,
                                                    float* __restrict__ dinv) {
    __shared__ int s[256];
    int t = threadIdx.x;
    int i = blockIdx.x * 256 + t;
    int d = (i < N_NODES) ? degFill[i] : 0;
    s[t] = d;
    __syncthreads();
    for (int off = 1; off < 256; off <<= 1) {
        int a = (t >= off) ? s[t - off] : 0;
        __syncthreads();
        s[t] += a;
        __syncthreads();
    }
    int excl = s[t] - d + blockSums[blockIdx.x];
    if (i < N_NODES) {
        rowPtr[i]  = excl;
        degFill[i] = excl;
        dinv[i]    = 1.0f / sqrtf((float)(d + 1));
    }
    if (i == 0) rowPtr[N_NODES] = N_EDGES;        // all edges retained
}

// ---------------------------------------------------------------------------
// K2: CSR fill (colIdx[pos] = src for each dst)
// ---------------------------------------------------------------------------
__global__ void fill_kernel(const int* __restrict__ ei,
                            int* __restrict__ fillPtr, int* __restrict__ colIdx) {
    int e = blockIdx.x * blockDim.x + threadIdx.x;
    if (e < N_EDGES) {
        int src = ei[e];
        int dst = ei[N_EDGES + e];
        int pos = atomicAdd(&fillPtr[dst], 1);
        colIdx[pos] = src;
    }
}

// ---------------------------------------------------------------------------
// K3/K5: g = (A @ W) * dinv[row]     A:[N,K]  W:[K,64]  g:[N,64]
// ---------------------------------------------------------------------------
#define FMA4(xs, w, a) { (a).x = fmaf((xs), (w).x, (a).x); \
                         (a).y = fmaf((xs), (w).y, (a).y); \
                         (a).z = fmaf((xs), (w).z, (a).z); \
                         (a).w = fmaf((xs), (w).w, (a).w); }

template <int K>
__global__ __launch_bounds__(256) void gemm_kernel(const float* __restrict__ A,
                                                   const float* __restrict__ W,
                                                   const float* __restrict__ dinv,
                                                   float* __restrict__ out) {
    __shared__ float4 Ws[K * 16];                 // [K][64] floats as float4[16]
    for (int i = threadIdx.x; i < K * 16; i += 256)
        Ws[i] = ((const float4*)W)[i];
    __syncthreads();

    const int c4   = threadIdx.x & 15;
    const int rg   = threadIdx.x >> 4;            // 0..15
    const int row0 = blockIdx.x * 128 + rg * 8;

    const float4* ap[8];
#pragma unroll
    for (int r = 0; r < 8; ++r) {
        int rowc = min(row0 + r, N_NODES - 1);    // clamp: OOB rows load row N-1
        ap[r] = (const float4*)(A + (size_t)rowc * K);
    }

    float4 acc[8] = {};
    for (int kk = 0; kk < K / 4; ++kk) {
        float4 xv[8];
#pragma unroll
        for (int r = 0; r < 8; ++r) xv[r] = ap[r][kk];
        float4 w;
        w = Ws[(4 * kk + 0) * 16 + c4];
#pragma unroll
        for (int r = 0; r < 8; ++r) FMA4(xv[r].x, w, acc[r]);
        w = Ws[(4 * kk + 1) * 16 + c4];
#pragma unroll
        for (int r = 0; r < 8; ++r) FMA4(xv[r].y, w, acc[r]);
        w = Ws[(4 * kk + 2) * 16 + c4];
#pragma unroll
        for (int r = 0; r < 8; ++r) FMA4(xv[r].z, w, acc[r]);
        w = Ws[(4 * kk + 3) * 16 + c4];
#pragma unroll
        for (int r = 0; r < 8; ++r) FMA4(xv[r].w, w, acc[r]);
    }

#pragma unroll
    for (int r = 0; r < 8; ++r) {
        int row = row0 + r;
        if (row < N_NODES) {
            float dv = dinv[row];
            float4 o = acc[r];
            o.x *= dv; o.y *= dv; o.z *= dv; o.w *= dv;
            ((float4*)(out + (size_t)row * HID))[c4] = o;
        }
    }
}

// ---------------------------------------------------------------------------
// K4/K6: aggregation. One wave per node, lane = channel.
// out[v] = relu(dinv[v] * (g[v] + sum_{u->v} g[u]) + bias)
// ---------------------------------------------------------------------------
__global__ __launch_bounds__(256) void agg_kernel(const float* __restrict__ g,
                                                  const float* __restrict__ dinv,
                                                  const int* __restrict__ rowPtr,
                                                  const int* __restrict__ colIdx,
                                                  const float* __restrict__ bias,
                                                  float* __restrict__ out) {
    int lane = threadIdx.x & 63;
    int v = blockIdx.x * 4 + (threadIdx.x >> 6);
    if (v >= N_NODES) return;

    float acc = g[(size_t)v * HID + lane];
    int e  = rowPtr[v];
    int e1 = rowPtr[v + 1];
    for (; e + 3 < e1; e += 4) {
        int u0 = colIdx[e], u1 = colIdx[e + 1], u2 = colIdx[e + 2], u3 = colIdx[e + 3];
        float a0 = g[(size_t)u0 * HID + lane];
        float a1 = g[(size_t)u1 * HID + lane];
        float a2 = g[(size_t)u2 * HID + lane];
        float a3 = g[(size_t)u3 * HID + lane];
        acc += (a0 + a1) + (a2 + a3);
    }
    for (; e < e1; ++e) acc += g[(size_t)colIdx[e] * HID + lane];

    float r = dinv[v] * acc + bias[lane];
    out[(size_t)v * HID + lane] = fmaxf(r, 0.f);
}

// ---------------------------------------------------------------------------
// K7a: grid-wide partial pool. Wave = 64 channels; each wave walks 64 rows of
// its block's 256-row chunk (stride 4). batch sorted -> graph id non-decreasing
// along the walk -> flush partial sum on id change (1-2 atomics/wave typical).
// ---------------------------------------------------------------------------
__global__ __launch_bounds__(256) void pool1_kernel(const float* __restrict__ h,
                                                    const int* __restrict__ batch,
                                                    float* __restrict__ pooledSum) {
    int lane = threadIdx.x & 63;
    int w    = threadIdx.x >> 6;                  // 0..3
    int base = blockIdx.x * 256 + w;

    float acc = 0.f;
    int curg = -1;
    for (int k = 0; k < 64; ++k) {
        int row = base + k * 4;
        if (row >= N_NODES) break;
        int g = batch[row];                       // wave-uniform (same addr all lanes)
        if (g != curg) {
            if (curg >= 0) atomicAdd(&pooledSum[curg * HID + lane], acc);
            acc = 0.f;
            curg = g;
        }
        acc += h[(size_t)row * HID + lane];
    }
    if (curg >= 0) atomicAdd(&pooledSum[curg * HID + lane], acc);
}

// ---------------------------------------------------------------------------
// K7b: finalize. Block = one graph, 64 threads (lane = channel).
// pooled = pooledSum/count; head via 64-wide shuffle reduce.
// d_out layout: [ out (64x2) | pooled (64x64) ]
// ---------------------------------------------------------------------------
__global__ __launch_bounds__(64) void pool2_kernel(const float* __restrict__ pooledSum,
                                                   const int* __restrict__ batch,
                                                   const float* __restrict__ Wl,
                                                   const float* __restrict__ bl,
                                                   float* __restrict__ dout) {
    int g    = blockIdx.x;
    int lane = threadIdx.x;

    // count = bounds(g+1) - bounds(g), each lane computes both (redundant, cheap)
    int lo0 = 0, hi = N_NODES;
    while (lo0 < hi) { int mid = (lo0 + hi) >> 1; if (batch[mid] < g) lo0 = mid + 1; else hi = mid; }
    int lo1 = lo0; hi = N_NODES;
    while (lo1 < hi) { int mid = (lo1 + hi) >> 1; if (batch[mid] < g + 1) lo1 = mid + 1; else hi = mid; }
    float cnt = (float)(lo1 - lo0);

    float p = pooledSum[g * HID + lane] / fmaxf(cnt, 1.0f);
    dout[N_GRAPHS * N_CLASSES + g * HID + lane] = p;

    float p0 = p * Wl[lane * N_CLASSES + 0];
    float p1 = p * Wl[lane * N_CLASSES + 1];
#pragma unroll
    for (int off = 32; off > 0; off >>= 1) {
        p0 += __shfl_down(p0, off, 64);
        p1 += __shfl_down(p1, off, 64);
    }
    if (lane == 0) {
        dout[g * N_CLASSES + 0] = p0 + bl[0];
        dout[g * N_CLASSES + 1] = p1 + bl[1];
    }
}

// ---------------------------------------------------------------------------
extern "C" void kernel_launch(void* const* d_in, const int* in_sizes, int n_in,
                              void* d_out, int out_size, void* d_ws, size_t ws_size,
                              hipStream_t stream) {
    const float* x     = (const float*)d_in[0];
    const int*   ei    = (const int*)d_in[1];    // int32 on device
    const int*   batch = (const int*)d_in[2];    // int32 on device
    const float* W1    = (const float*)d_in[3];
    const float* b1    = (const float*)d_in[4];
    const float* W2    = (const float*)d_in[5];
    const float* b2    = (const float*)d_in[6];
    const float* Wl    = (const float*)d_in[7];
    const float* bl    = (const float*)d_in[8];
    float* out = (float*)d_out;

    char* ws = (char*)d_ws;
    size_t off = 0;
    auto alloc = [&](size_t bytes) -> void* {
        void* p = ws + off;
        off += (bytes + 255) & ~(size_t)255;
        return p;
    };
    int*   degFill   = (int*)  alloc((size_t)N_NODES * 4);        // counts -> fillPtr
    int*   rowPtr    = (int*)  alloc((size_t)(N_NODES + 1) * 4);
    float* dinv      = (float*)alloc((size_t)N_NODES * 4);
    int*   blockSums = (int*)  alloc((size_t)NBLK_SCAN * 4);
    float* pooledSum = (float*)alloc((size_t)N_GRAPHS * HID * 4);
    int*   colIdx    = (int*)  alloc((size_t)N_EDGES * 4);
    float* bufA      = (float*)alloc((size_t)N_NODES * HID * 4);  // g1 -> g2
    float* bufB      = (float*)alloc((size_t)N_NODES * HID * 4);  // h1 -> h2

    hipMemsetAsync(degFill, 0, (size_t)N_NODES * 4, stream);
    hipMemsetAsync(pooledSum, 0, (size_t)N_GRAPHS * HID * 4, stream);

    deg_kernel  <<<(N_EDGES + 255) / 256, 256, 0, stream>>>(ei, degFill);
    scan1_kernel<<<NBLK_SCAN, 256, 0, stream>>>(degFill, blockSums);
    scan2_kernel<<<1, 256, 0, stream>>>(blockSums);
    scan3_kernel<<<NBLK_SCAN, 256, 0, stream>>>(degFill, blockSums, rowPtr, dinv);
    fill_kernel <<<(N_EDGES + 255) / 256, 256, 0, stream>>>(ei, degFill, colIdx);

    // layer 1: g1 = (x@W1)*dinv ; h1 = relu(dinv*(g1[v]+sum g1[u]) + b1)
    gemm_kernel<IN_CH><<<(N_NODES + 127) / 128, 256, 0, stream>>>(x, W1, dinv, bufA);
    agg_kernel        <<<N_NODES / 4, 256, 0, stream>>>(bufA, dinv, rowPtr, colIdx, b1, bufB);

    // layer 2
    gemm_kernel<HID>  <<<(N_NODES + 127) / 128, 256, 0, stream>>>(bufB, W2, dinv, bufA);
    agg_kernel        <<<N_NODES / 4, 256, 0, stream>>>(bufA, dinv, rowPtr, colIdx, b2, bufB);

    // pool + head
    pool1_kernel<<<NBLK_SCAN, 256, 0, stream>>>(bufB, batch, pooledSum);
    pool2_kernel<<<N_GRAPHS, 64, 0, stream>>>(pooledSum, batch, Wl, bl, out);
}

// Round 6
// 323.392 us; speedup vs baseline: 1.4534x; 1.0296x over previous
//
#include <hip/hip_runtime.h>

#define N_NODES   50000
#define N_EDGES   800000
#define IN_CH     128
#define HID       64
#define N_GRAPHS  64
#define N_CLASSES 2
#define NBLK_SCAN ((N_NODES + 255) / 256)   // 196

// Round 3: single-block scan was 133 us -> 3-phase scan.
// Round 4: pool_kernel 59 us at 2.3% occupancy -> atomic partial pool + finalize.
// Round 5: fill_kernel 54 us, WRITE_SIZE 53 MB for a 3.2 MB colIdx (16x write
// amplification from cross-XCD scattered 4B stores) -> XCD-partitioned,
// dst-windowed fill: partition p = blockIdx&7 handles dst in [p*6250,(p+1)*6250).

// ---------------------------------------------------------------------------
// K0: in-degree count (real edges only; self-loop handled analytically)
// ---------------------------------------------------------------------------
__global__ void deg_kernel(const int* __restrict__ ei, int* __restrict__ degCount) {
    int e = blockIdx.x * blockDim.x + threadIdx.x;
    if (e < N_EDGES) {
        int dst = ei[N_EDGES + e];
        atomicAdd(&degCount[dst], 1);
    }
}

// ---------------------------------------------------------------------------
// K1a: per-256-chunk sums
// ---------------------------------------------------------------------------
__global__ __launch_bounds__(256) void scan1_kernel(const int* __restrict__ degCount,
                                                    int* __restrict__ blockSums) {
    __shared__ int red[256];
    int i = blockIdx.x * 256 + threadIdx.x;
    red[threadIdx.x] = (i < N_NODES) ? degCount[i] : 0;
    __syncthreads();
    for (int off = 128; off > 0; off >>= 1) {
        if (threadIdx.x < off) red[threadIdx.x] += red[threadIdx.x + off];
        __syncthreads();
    }
    if (threadIdx.x == 0) blockSums[blockIdx.x] = red[0];
}

// ---------------------------------------------------------------------------
// K1b: single-block exclusive scan over the 196 block sums
// ---------------------------------------------------------------------------
__global__ __launch_bounds__(256) void scan2_kernel(int* __restrict__ blockSums) {
    __shared__ int s[256];
    int t = threadIdx.x;
    int v = (t < NBLK_SCAN) ? blockSums[t] : 0;
    s[t] = v;
    __syncthreads();
    for (int off = 1; off < 256; off <<= 1) {
        int a = (t >= off) ? s[t - off] : 0;
        __syncthreads();
        s[t] += a;
        __syncthreads();
    }
    if (t < NBLK_SCAN) blockSums[t] = s[t] - v;   // exclusive prefix
}

// ---------------------------------------------------------------------------
// K1c: per-chunk exclusive scan + block offset -> rowPtr, fillPtr (aliased
//      onto degCount), dinv = (deg+1)^-0.5
// ---------------------------------------------------------------------------
__global__ __launch_bounds__(256) void scan3_kernel(int* __restrict__ degFill,
                                                    const int* __restrict__ blockSums,
                                                    int* __restrict__ rowPtr,
                                                    float* __restrict__ dinv) {
    __shared__ int s[256];
    int t = threadIdx.x;
    int i = blockIdx.x * 256 + t;
    int d = (i < N_NODES) ? degFill[i] : 0;
    s[t] = d;
    __syncthreads();
    for (int off = 1; off < 256; off <<= 1) {
        int a = (t >= off) ? s[t - off] : 0;
        __syncthreads();
        s[t] += a;
        __syncthreads();
    }
    int excl = s[t] - d + blockSums[blockIdx.x];
    if (i < N_NODES) {
        rowPtr[i]  = excl;
        degFill[i] = excl;
        dinv[i]    = 1.0f / sqrtf((float)(d + 1));
    }
    if (i == 0) rowPtr[N_NODES] = N_EDGES;        // all edges retained
}

// ---------------------------------------------------------------------------
// K2: CSR fill, XCD-partitioned + dst-windowed.
// part = blockIdx&7 (round-robins onto the 8 XCDs); each partition owns dst in
// [part*6250, (part+1)*6250) so its colIdx window (~400KB) stays in ONE XCD's
// L2 and lines fill before eviction. 391 chunk-blocks per partition sweep the
// full edge list (dst re-reads are L2/L3-served).
// ---------------------------------------------------------------------------
#define FILL_CHUNKS ((N_EDGES + 2047) / 2048)     // 391
__global__ __launch_bounds__(256) void fill_kernel(const int* __restrict__ ei,
                                                   int* __restrict__ fillPtr,
                                                   int* __restrict__ colIdx) {
    int part = blockIdx.x & 7;
    int blk  = blockIdx.x >> 3;                   // 0..390
    int lo   = part * 6250;
    int hi   = lo + 6250;
#pragma unroll
    for (int it = 0; it < 8; ++it) {
        int e = blk * 2048 + it * 256 + (int)threadIdx.x;
        if (e < N_EDGES) {
            int dst = ei[N_EDGES + e];
            if (dst >= lo && dst < hi) {
                int src = ei[e];
                int pos = atomicAdd(&fillPtr[dst], 1);
                colIdx[pos] = src;
            }
        }
    }
}

// ---------------------------------------------------------------------------
// K3/K5: g = (A @ W) * dinv[row]     A:[N,K]  W:[K,64]  g:[N,64]
// ---------------------------------------------------------------------------
#define FMA4(xs, w, a) { (a).x = fmaf((xs), (w).x, (a).x); \
                         (a).y = fmaf((xs), (w).y, (a).y); \
                         (a).z = fmaf((xs), (w).z, (a).z); \
                         (a).w = fmaf((xs), (w).w, (a).w); }

template <int K>
__global__ __launch_bounds__(256) void gemm_kernel(const float* __restrict__ A,
                                                   const float* __restrict__ W,
                                                   const float* __restrict__ dinv,
                                                   float* __restrict__ out) {
    __shared__ float4 Ws[K * 16];                 // [K][64] floats as float4[16]
    for (int i = threadIdx.x; i < K * 16; i += 256)
        Ws[i] = ((const float4*)W)[i];
    __syncthreads();

    const int c4   = threadIdx.x & 15;
    const int rg   = threadIdx.x >> 4;            // 0..15
    const int row0 = blockIdx.x * 128 + rg * 8;

    const float4* ap[8];
#pragma unroll
    for (int r = 0; r < 8; ++r) {
        int rowc = min(row0 + r, N_NODES - 1);    // clamp: OOB rows load row N-1
        ap[r] = (const float4*)(A + (size_t)rowc * K);
    }

    float4 acc[8] = {};
    for (int kk = 0; kk < K / 4; ++kk) {
        float4 xv[8];
#pragma unroll
        for (int r = 0; r < 8; ++r) xv[r] = ap[r][kk];
        float4 w;
        w = Ws[(4 * kk + 0) * 16 + c4];
#pragma unroll
        for (int r = 0; r < 8; ++r) FMA4(xv[r].x, w, acc[r]);
        w = Ws[(4 * kk + 1) * 16 + c4];
#pragma unroll
        for (int r = 0; r < 8; ++r) FMA4(xv[r].y, w, acc[r]);
        w = Ws[(4 * kk + 2) * 16 + c4];
#pragma unroll
        for (int r = 0; r < 8; ++r) FMA4(xv[r].z, w, acc[r]);
        w = Ws[(4 * kk + 3) * 16 + c4];
#pragma unroll
        for (int r = 0; r < 8; ++r) FMA4(xv[r].w, w, acc[r]);
    }

#pragma unroll
    for (int r = 0; r < 8; ++r) {
        int row = row0 + r;
        if (row < N_NODES) {
            float dv = dinv[row];
            float4 o = acc[r];
            o.x *= dv; o.y *= dv; o.z *= dv; o.w *= dv;
            ((float4*)(out + (size_t)row * HID))[c4] = o;
        }
    }
}

// ---------------------------------------------------------------------------
// K4/K6: aggregation. One wave per node, lane = channel.
// out[v] = relu(dinv[v] * (g[v] + sum_{u->v} g[u]) + bias)
// ---------------------------------------------------------------------------
__global__ __launch_bounds__(256) void agg_kernel(const float* __restrict__ g,
                                                  const float* __restrict__ dinv,
                                                  const int* __restrict__ rowPtr,
                                                  const int* __restrict__ colIdx,
                                                  const float* __restrict__ bias,
                                                  float* __restrict__ out) {
    int lane = threadIdx.x & 63;
    int v = blockIdx.x * 4 + (threadIdx.x >> 6);
    if (v >= N_NODES) return;

    float acc = g[(size_t)v * HID + lane];
    int e  = rowPtr[v];
    int e1 = rowPtr[v + 1];
    for (; e + 3 < e1; e += 4) {
        int u0 = colIdx[e], u1 = colIdx[e + 1], u2 = colIdx[e + 2], u3 = colIdx[e + 3];
        float a0 = g[(size_t)u0 * HID + lane];
        float a1 = g[(size_t)u1 * HID + lane];
        float a2 = g[(size_t)u2 * HID + lane];
        float a3 = g[(size_t)u3 * HID + lane];
        acc += (a0 + a1) + (a2 + a3);
    }
    for (; e < e1; ++e) acc += g[(size_t)colIdx[e] * HID + lane];

    float r = dinv[v] * acc + bias[lane];
    out[(size_t)v * HID + lane] = fmaxf(r, 0.f);
}

// ---------------------------------------------------------------------------
// K7a: grid-wide partial pool (flush-on-graph-change; batch sorted).
// ---------------------------------------------------------------------------
__global__ __launch_bounds__(256) void pool1_kernel(const float* __restrict__ h,
                                                    const int* __restrict__ batch,
                                                    float* __restrict__ pooledSum) {
    int lane = threadIdx.x & 63;
    int w    = threadIdx.x >> 6;                  // 0..3
    int base = blockIdx.x * 256 + w;

    float acc = 0.f;
    int curg = -1;
    for (int k = 0; k < 64; ++k) {
        int row = base + k * 4;
        if (row >= N_NODES) break;
        int g = batch[row];                       // wave-uniform
        if (g != curg) {
            if (curg >= 0) atomicAdd(&pooledSum[curg * HID + lane], acc);
            acc = 0.f;
            curg = g;
        }
        acc += h[(size_t)row * HID + lane];
    }
    if (curg >= 0) atomicAdd(&pooledSum[curg * HID + lane], acc);
}

// ---------------------------------------------------------------------------
// K7b: finalize. Block = one graph, 64 threads (lane = channel).
// d_out layout: [ out (64x2) | pooled (64x64) ]
// ---------------------------------------------------------------------------
__global__ __launch_bounds__(64) void pool2_kernel(const float* __restrict__ pooledSum,
                                                   const int* __restrict__ batch,
                                                   const float* __restrict__ Wl,
                                                   const float* __restrict__ bl,
                                                   float* __restrict__ dout) {
    int g    = blockIdx.x;
    int lane = threadIdx.x;

    int lo0 = 0, hi = N_NODES;
    while (lo0 < hi) { int mid = (lo0 + hi) >> 1; if (batch[mid] < g) lo0 = mid + 1; else hi = mid; }
    int lo1 = lo0; hi = N_NODES;
    while (lo1 < hi) { int mid = (lo1 + hi) >> 1; if (batch[mid] < g + 1) lo1 = mid + 1; else hi = mid; }
    float cnt = (float)(lo1 - lo0);

    float p = pooledSum[g * HID + lane] / fmaxf(cnt, 1.0f);
    dout[N_GRAPHS * N_CLASSES + g * HID + lane] = p;

    float p0 = p * Wl[lane * N_CLASSES + 0];
    float p1 = p * Wl[lane * N_CLASSES + 1];
#pragma unroll
    for (int off = 32; off > 0; off >>= 1) {
        p0 += __shfl_down(p0, off, 64);
        p1 += __shfl_down(p1, off, 64);
    }
    if (lane == 0) {
        dout[g * N_CLASSES + 0] = p0 + bl[0];
        dout[g * N_CLASSES + 1] = p1 + bl[1];
    }
}

// ---------------------------------------------------------------------------
extern "C" void kernel_launch(void* const* d_in, const int* in_sizes, int n_in,
                              void* d_out, int out_size, void* d_ws, size_t ws_size,
                              hipStream_t stream) {
    const float* x     = (const float*)d_in[0];
    const int*   ei    = (const int*)d_in[1];    // int32 on device
    const int*   batch = (const int*)d_in[2];    // int32 on device
    const float* W1    = (const float*)d_in[3];
    const float* b1    = (const float*)d_in[4];
    const float* W2    = (const float*)d_in[5];
    const float* b2    = (const float*)d_in[6];
    const float* Wl    = (const float*)d_in[7];
    const float* bl    = (const float*)d_in[8];
    float* out = (float*)d_out;

    char* ws = (char*)d_ws;
    size_t off = 0;
    auto alloc = [&](size_t bytes) -> void* {
        void* p = ws + off;
        off += (bytes + 255) & ~(size_t)255;
        return p;
    };
    int*   degFill   = (int*)  alloc((size_t)N_NODES * 4);        // counts -> fillPtr
    int*   rowPtr    = (int*)  alloc((size_t)(N_NODES + 1) * 4);
    float* dinv      = (float*)alloc((size_t)N_NODES * 4);
    int*   blockSums = (int*)  alloc((size_t)NBLK_SCAN * 4);
    float* pooledSum = (float*)alloc((size_t)N_GRAPHS * HID * 4);
    int*   colIdx    = (int*)  alloc((size_t)N_EDGES * 4);
    float* bufA      = (float*)alloc((size_t)N_NODES * HID * 4);  // g1 -> g2
    float* bufB      = (float*)alloc((size_t)N_NODES * HID * 4);  // h1 -> h2

    hipMemsetAsync(degFill, 0, (size_t)N_NODES * 4, stream);
    hipMemsetAsync(pooledSum, 0, (size_t)N_GRAPHS * HID * 4, stream);

    deg_kernel  <<<(N_EDGES + 255) / 256, 256, 0, stream>>>(ei, degFill);
    scan1_kernel<<<NBLK_SCAN, 256, 0, stream>>>(degFill, blockSums);
    scan2_kernel<<<1, 256, 0, stream>>>(blockSums);
    scan3_kernel<<<NBLK_SCAN, 256, 0, stream>>>(degFill, blockSums, rowPtr, dinv);
    fill_kernel <<<FILL_CHUNKS * 8, 256, 0, stream>>>(ei, degFill, colIdx);

    // layer 1: g1 = (x@W1)*dinv ; h1 = relu(dinv*(g1[v]+sum g1[u]) + b1)
    gemm_kernel<IN_CH><<<(N_NODES + 127) / 128, 256, 0, stream>>>(x, W1, dinv, bufA);
    agg_kernel        <<<N_NODES / 4, 256, 0, stream>>>(bufA, dinv, rowPtr, colIdx, b1, bufB);

    // layer 2
    gemm_kernel<HID>  <<<(N_NODES + 127) / 128, 256, 0, stream>>>(bufB, W2, dinv, bufA);
    agg_kernel        <<<N_NODES / 4, 256, 0, stream>>>(bufA, dinv, rowPtr, colIdx, b2, bufB);

    // pool + head
    pool1_kernel<<<NBLK_SCAN, 256, 0, stream>>>(bufB, batch, pooledSum);
    pool2_kernel<<<N_GRAPHS, 64, 0, stream>>>(pooledSum, batch, Wl, bl, out);
}